// Round 1
// 4260.052 us; speedup vs baseline: 1.1634x; 1.1634x over previous
//
#include <hip/hip_runtime.h>
#include <math.h>

typedef __attribute__((ext_vector_type(8))) short short8;
typedef __attribute__((ext_vector_type(4))) float f32x4;

__device__ __forceinline__ float bf2f(unsigned short u) {
    union { unsigned int i; float f; } x; x.i = ((unsigned int)u) << 16; return x.f;
}
__device__ __forceinline__ unsigned short f2bf(float f) {
    union { float f; unsigned int i; } x; x.f = f;
    unsigned int i = x.i;
    return (unsigned short)((i + 0x7fffu + ((i >> 16) & 1u)) >> 16);
}

// ---------------------------------------------------------------------------
// dtype sniffer: decides whether inputs are bf16-packed or fp32.
// Reads first 4096 u32 words of W_obs (safe: >=256KB in either mode).
// bf16 data: low short's exponent field sits in a narrow band -> ~100% hits.
// fp32 data: low short is random mantissa bits -> ~10% hits.
// flag = 1 (bf16) / 0 (fp32)
// ---------------------------------------------------------------------------
__global__ __launch_bounds__(256) void sniff_dtype(const unsigned int* __restrict__ w,
                                                   int* __restrict__ flag)
{
    __shared__ int red[4];
    int t = threadIdx.x;
    int hits = 0;
    for (int u = 0; u < 16; ++u) {
        unsigned int word = w[t * 16 + u];
        unsigned int ex = (word >> 7) & 0xFFu;   // exponent field of LOW short as bf16
        if (ex >= 100u && ex <= 126u) ++hits;
    }
#pragma unroll
    for (int off = 32; off >= 1; off >>= 1) hits += __shfl_xor(hits, off, 64);
    if ((t & 63) == 0) red[t >> 6] = hits;
    __syncthreads();
    if (t == 0) flag[0] = ((red[0] + red[1] + red[2] + red[3]) > 2048) ? 1 : 0;
}

// convert n elements of src (starting at element elem_off) to bf16 in dst
__global__ __launch_bounds__(256) void cvt_in(const void* __restrict__ src, size_t elem_off,
                                              unsigned short* __restrict__ dst, int n,
                                              const int* __restrict__ flag)
{
    int i = (blockIdx.x * 256 + threadIdx.x) * 4;
    int m = *flag;
    if (i + 3 < n) {
        if (m) {
            const unsigned short* s = (const unsigned short*)src + elem_off + i;
            *(ushort4*)(dst + i) = *(const ushort4*)s;
        } else {
            const float* s = (const float*)src + elem_off + i;
            float4 v = *(const float4*)s;
            ushort4 o; o.x = f2bf(v.x); o.y = f2bf(v.y); o.z = f2bf(v.z); o.w = f2bf(v.w);
            *(ushort4*)(dst + i) = o;
        }
    } else {
        for (int u = i; u < n; ++u) {
            if (m) dst[u] = ((const unsigned short*)src)[elem_off + u];
            else   dst[u] = f2bf(((const float*)src)[elem_off + u]);
        }
    }
}

// write output: bf16 result -> d_out in the detected dtype; scrub non-finite to 1000
__global__ __launch_bounds__(256) void write_out(const unsigned short* __restrict__ src,
                                                 void* __restrict__ dst, int n,
                                                 const int* __restrict__ flag)
{
    int i = blockIdx.x * 256 + threadIdx.x;
    if (i >= n) return;
    unsigned short u = src[i];
    if ((u & 0x7F80u) == 0x7F80u) u = 0x447Au;   // sentinel 1000.0 for NaN/Inf
    if (*flag) ((unsigned short*)dst)[i] = u;
    else       ((float*)dst)[i] = bf2f(u);
}

// ---------------------------------------------------------------------------
// GEMM: C[M,N] = A[M,K] @ B[N,K]^T (+bias, optional ReLU), bf16 in/out, fp32 acc
// ---------------------------------------------------------------------------
__global__ __launch_bounds__(256) void gemm_bt(
    const unsigned short* __restrict__ A,
    const unsigned short* __restrict__ B,
    const unsigned short* __restrict__ bias,
    unsigned short* __restrict__ C,
    int M, int N, int K, int relu)
{
    __shared__ __align__(16) unsigned short As[128 * 32];
    __shared__ __align__(16) unsigned short Bs[128 * 32];
    const int t = threadIdx.x;
    const int lane = t & 63;
    const int w = t >> 6;
    const int la = lane & 15;
    const int quad = lane >> 4;
    const int m0 = blockIdx.y * 128;
    const int n0 = blockIdx.x * 128;
    const int wm = (w >> 1) * 64;
    const int wn = (w & 1) * 64;
    f32x4 acc[4][4];
#pragma unroll
    for (int i = 0; i < 4; ++i)
#pragma unroll
        for (int j = 0; j < 4; ++j) acc[i][j] = (f32x4){0.f, 0.f, 0.f, 0.f};

    const int row0 = t >> 2, seg0 = t & 3;
    const unsigned short* Ap = A + (size_t)(m0 + row0) * K + seg0 * 8;
    const unsigned short* Bp = B + (size_t)(n0 + row0) * K + seg0 * 8;

    for (int kt = 0; kt < K; kt += 32) {
        __syncthreads();
        {
            int4 va0 = *(const int4*)(Ap + kt);
            int4 va1 = *(const int4*)(Ap + (size_t)64 * K + kt);
            int4 vb0 = *(const int4*)(Bp + kt);
            int4 vb1 = *(const int4*)(Bp + (size_t)64 * K + kt);
            *(int4*)(As + row0 * 32 + seg0 * 8) = va0;
            *(int4*)(As + (row0 + 64) * 32 + seg0 * 8) = va1;
            *(int4*)(Bs + row0 * 32 + seg0 * 8) = vb0;
            *(int4*)(Bs + (row0 + 64) * 32 + seg0 * 8) = vb1;
        }
        __syncthreads();
        short8 af[4], bfr[4];
#pragma unroll
        for (int i = 0; i < 4; ++i)
            af[i] = *(const short8*)(As + (wm + i * 16 + la) * 32 + quad * 8);
#pragma unroll
        for (int j = 0; j < 4; ++j)
            bfr[j] = *(const short8*)(Bs + (wn + j * 16 + la) * 32 + quad * 8);
#pragma unroll
        for (int i = 0; i < 4; ++i)
#pragma unroll
            for (int j = 0; j < 4; ++j)
                acc[i][j] = __builtin_amdgcn_mfma_f32_16x16x32_bf16(af[i], bfr[j], acc[i][j], 0, 0, 0);
    }

#pragma unroll
    for (int j = 0; j < 4; ++j) {
        int n = n0 + wn + j * 16 + la;
        float bv = bias ? bf2f(bias[n]) : 0.0f;
#pragma unroll
        for (int i = 0; i < 4; ++i) {
#pragma unroll
            for (int r = 0; r < 4; ++r) {
                int m = m0 + wm + i * 16 + quad * 4 + r;
                float v = acc[i][j][r] + bv;
                if (relu) v = fmaxf(v, 0.0f);
                C[(size_t)m * N + n] = f2bf(v);
            }
        }
    }
}

// ---------------------------------------------------------------------------
// Fused attention: one block = 16 queries of one (b,h). Full 512-key softmax.
// ---------------------------------------------------------------------------
__global__ __launch_bounds__(256) void attn_kernel(
    const unsigned short* __restrict__ qkv,
    unsigned short* __restrict__ attn_out)
{
    __shared__ __align__(16) unsigned short Qs[16 * 64];
    __shared__ __align__(16) unsigned short Ks[128 * 64];   // reused as P [16*512]
    __shared__ float Ss[16 * 512];
    __shared__ __align__(16) unsigned short Vt[64 * 48];    // V^T tile, stride 48
    __shared__ float Linv[16];

    const int t = threadIdx.x;
    const int lane = t & 63;
    const int w = t >> 6;
    const int la = lane & 15;
    const int quad = lane >> 4;
    const int qt = blockIdx.x;
    const int bh = blockIdx.y;
    const int b = bh >> 4, h = bh & 15;
    const int q0 = qt * 16;
    const size_t rowbase = (size_t)b * 512;
    const int qoff = h * 192, koff = h * 192 + 64, voff = h * 192 + 128;

    if (t < 128) {
        int r = t >> 3, c8 = t & 7;
        int4 v = *(const int4*)(qkv + (rowbase + q0 + r) * 3072 + qoff + c8 * 8);
        *(int4*)(Qs + r * 64 + c8 * 8) = v;
    }
    __syncthreads();
    short8 aq[2];
#pragma unroll
    for (int dc = 0; dc < 2; ++dc)
        aq[dc] = *(const short8*)(Qs + la * 64 + dc * 32 + quad * 8);

    for (int kt = 0; kt < 4; ++kt) {
        __syncthreads();
#pragma unroll
        for (int it = 0; it < 4; ++it) {
            int idx = it * 256 + t;
            int r = idx >> 3, c8 = idx & 7;
            int4 v = *(const int4*)(qkv + (rowbase + kt * 128 + r) * 3072 + koff + c8 * 8);
            *(int4*)(Ks + r * 64 + c8 * 8) = v;
        }
        __syncthreads();
#pragma unroll
        for (int u = 0; u < 2; ++u) {
            int tile = w * 2 + u;
            f32x4 acc = (f32x4){0.f, 0.f, 0.f, 0.f};
#pragma unroll
            for (int dc = 0; dc < 2; ++dc) {
                short8 bb = *(const short8*)(Ks + (tile * 16 + la) * 64 + dc * 32 + quad * 8);
                acc = __builtin_amdgcn_mfma_f32_16x16x32_bf16(aq[dc], bb, acc, 0, 0, 0);
            }
            int kk = kt * 128 + tile * 16 + la;
#pragma unroll
            for (int r = 0; r < 4; ++r)
                Ss[(quad * 4 + r) * 512 + kk] = acc[r] * 0.125f;
        }
    }
    __syncthreads();

    unsigned short* Ps = Ks;
    {
        int row = t >> 4, c = t & 15;
        int base = c * 32;
        float mx = -1e30f;
        for (int i2 = 0; i2 < 32; ++i2) mx = fmaxf(mx, Ss[row * 512 + base + i2]);
#pragma unroll
        for (int off = 8; off >= 1; off >>= 1) mx = fmaxf(mx, __shfl_xor(mx, off, 64));
        float sum = 0.f;
        for (int i2 = 0; i2 < 32; ++i2) {
            float e = __expf(Ss[row * 512 + base + i2] - mx);
            sum += e;
            Ps[row * 512 + base + i2] = f2bf(e);
        }
#pragma unroll
        for (int off = 8; off >= 1; off >>= 1) sum += __shfl_xor(sum, off, 64);
        if (c == 0) Linv[row] = 1.0f / sum;
    }

    f32x4 oacc = (f32x4){0.f, 0.f, 0.f, 0.f};
    const int dbase = w * 16;
    for (int kc = 0; kc < 16; ++kc) {
        __syncthreads();
        {
            int r = t >> 3, c8 = t & 7;
            int4 v = *(const int4*)(qkv + (rowbase + kc * 32 + r) * 3072 + voff + c8 * 8);
            union { int4 v4; unsigned short s[8]; } tmp; tmp.v4 = v;
#pragma unroll
            for (int u2 = 0; u2 < 8; ++u2)
                Vt[(c8 * 8 + u2) * 48 + r] = tmp.s[u2];
        }
        __syncthreads();
        short8 a = *(const short8*)(Ps + la * 512 + kc * 32 + quad * 8);
        short8 bb = *(const short8*)(Vt + (dbase + la) * 48 + quad * 8);
        oacc = __builtin_amdgcn_mfma_f32_16x16x32_bf16(a, bb, oacc, 0, 0, 0);
    }
    {
        int d = h * 64 + dbase + la;
#pragma unroll
        for (int r = 0; r < 4; ++r) {
            int q = quad * 4 + r;
            float v = oacc[r] * Linv[q];
            attn_out[(rowbase + q0 + q) * 1024 + d] = f2bf(v);
        }
    }
}

// ---------------------------------------------------------------------------
// residual + LayerNorm, bf16 in/out (in-place on z), fp32 internals
// ---------------------------------------------------------------------------
__global__ __launch_bounds__(256) void resid_ln(
    const unsigned short* __restrict__ z_in, const unsigned short* __restrict__ br,
    const unsigned short* __restrict__ g, const unsigned short* __restrict__ bb,
    unsigned short* __restrict__ z_out)
{
    __shared__ float red[4];
    const int m = blockIdx.x, t = threadIdx.x;
    float v[4];
#pragma unroll
    for (int u = 0; u < 4; ++u) {
        int e = t + u * 256;
        v[u] = bf2f(z_in[(size_t)m * 1024 + e]) + bf2f(br[(size_t)m * 1024 + e]);
    }
    float s = v[0] + v[1] + v[2] + v[3];
#pragma unroll
    for (int off = 32; off >= 1; off >>= 1) s += __shfl_xor(s, off, 64);
    if ((t & 63) == 0) red[t >> 6] = s;
    __syncthreads();
    float mean = (red[0] + red[1] + red[2] + red[3]) * (1.0f / 1024.0f);
    __syncthreads();
    float q = 0.f;
#pragma unroll
    for (int u = 0; u < 4; ++u) { float d = v[u] - mean; q += d * d; }
#pragma unroll
    for (int off = 32; off >= 1; off >>= 1) q += __shfl_xor(q, off, 64);
    if ((t & 63) == 0) red[t >> 6] = q;
    __syncthreads();
    float var = (red[0] + red[1] + red[2] + red[3]) * (1.0f / 1024.0f);
    float inv = rsqrtf(var + 1e-5f);
#pragma unroll
    for (int u = 0; u < 4; ++u) {
        int e = t + u * 256;
        float o = (v[u] - mean) * inv * bf2f(g[e]) + bf2f(bb[e]);
        z_out[(size_t)m * 1024 + e] = f2bf(o);
    }
}

// ---------------------------------------------------------------------------
// pinv pieces (inputs already converted to bf16)
// ---------------------------------------------------------------------------
__global__ void transpose_wobs(const unsigned short* __restrict__ W, unsigned short* __restrict__ WT)
{
    int idx = blockIdx.x * 256 + threadIdx.x;     // 131072 total
    int o = idx >> 10, e = idx & 1023;
    WT[e * 128 + o] = W[idx];
}

__global__ void compute_G(const unsigned short* __restrict__ WT, float* __restrict__ G)
{
    int i = blockIdx.x, j = threadIdx.x;          // 128 x 128
    float s = 0.f;
    for (int e = 0; e < 1024; ++e)
        s += bf2f(WT[e * 128 + i]) * bf2f(WT[e * 128 + j]);
    G[i * 128 + j] = s;
}

// sweep operator: sweeping all pivots of SPD A in place yields -A^{-1}
// Thread->element map: column j = t&127 (stride-1 across a wave's lanes ->
// conflict-free LDS), rows i = (t>>7) + 8u. Col-k snapshot reads are
// wave-uniform (broadcast, free). Old map (i=t>>3, j0=(t&7)*16) put a wave's
// 64 lanes on 2 banks -> 32-way conflict on every access (2.0M conflict
// cycles measured = ~100% of the 923us runtime).
__global__ __launch_bounds__(1024) void sweep_inv(const float* __restrict__ G, float* __restrict__ Gi)
{
    __shared__ float M[128 * 128];                // 64 KB
    const int t = threadIdx.x;
    for (int i = t; i < 16384; i += 1024) M[i] = G[i];
    __syncthreads();
    const int j = t & 127;                        // column (consecutive within wave)
    const int ib = t >> 7;                        // row base 0..7 (wave-uniform)
    for (int k = 0; k < 128; ++k) {
        float d = M[k * 128 + k];                 // broadcast
        float p = 1.0f / d;
        float rj = M[k * 128 + j];                // row-k snapshot, conflict-free
        float cv[16];
#pragma unroll
        for (int u = 0; u < 16; ++u)
            cv[u] = M[(ib + u * 8) * 128 + k];    // col-k snapshot, broadcast
        __syncthreads();
#pragma unroll
        for (int u = 0; u < 16; ++u) {
            int i = ib + u * 8;
            float nv;
            if (i == k && j == k)      nv = -p;
            else if (i == k)           nv = rj * p;
            else if (j == k)           nv = cv[u] * p;
            else                       nv = M[i * 128 + j] - cv[u] * rj * p;
            M[i * 128 + j] = nv;                  // conflict-free
        }
        __syncthreads();
    }
    for (int n = t; n < 16384; n += 1024) Gi[n] = -M[n];
}

__global__ void embed_y(const unsigned short* __restrict__ x, const float* __restrict__ Gi,
                        float* __restrict__ y)
{
    int m = blockIdx.x, t = threadIdx.x;  // 128 threads
    float s = 0.f;
    for (int o = 0; o < 128; ++o)
        s += bf2f(x[(size_t)m * 128 + o]) * Gi[o * 128 + t];
    y[(size_t)m * 128 + t] = s;
}

__global__ __launch_bounds__(256) void embed_z(const float* __restrict__ y,
                                               const unsigned short* __restrict__ Wobs,
                                               unsigned short* __restrict__ zb)
{
    int m = blockIdx.x, t = threadIdx.x;
    int s = m & 511;
    float accv[4] = {0.f, 0.f, 0.f, 0.f};
    for (int o = 0; o < 128; ++o) {
        float yv = y[(size_t)m * 128 + o];
#pragma unroll
        for (int u = 0; u < 4; ++u) {
            int e = t + u * 256;
            accv[u] += yv * bf2f(Wobs[o * 1024 + e]);
        }
    }
#pragma unroll
    for (int u = 0; u < 4; ++u) {
        int e = t + u * 256;
        float freq = __expf(-0.008994473019508f * (float)(e & ~1));
        float ang = (float)s * freq;
        float pe = (e & 1) ? cosf(ang) : sinf(ang);
        float v = accv[u] + pe;
        zb[(size_t)m * 1024 + e] = f2bf(v);
    }
}

// ---------------------------------------------------------------------------
extern "C" void kernel_launch(void* const* d_in, const int* in_sizes, int n_in,
                              void* d_out, int out_size, void* d_ws, size_t ws_size,
                              hipStream_t stream)
{
    const void* x_raw     = d_in[0];
    const void* Wobs_raw  = d_in[1];
    const void* Wqkv_raw  = d_in[2];
    const void* Wo_raw    = d_in[3];
    const void* bo_raw    = d_in[4];
    const void* ln1g_raw  = d_in[5];
    const void* ln1b_raw  = d_in[6];
    const void* W1_raw    = d_in[7];
    const void* b1_raw    = d_in[8];
    const void* W2_raw    = d_in[9];
    const void* b2_raw    = d_in[10];
    const void* ln2g_raw  = d_in[11];
    const void* ln2b_raw  = d_in[12];

    char* ws = (char*)d_ws;
    constexpr size_t OFF_G    = 0;                                  // 64 KB
    constexpr size_t OFF_GI   = OFF_G    + 65536;                   // 64 KB
    constexpr size_t OFF_Y    = OFF_GI   + 65536;                   // 2 MB fp32
    constexpr size_t OFF_WT   = OFF_Y    + (size_t)4096 * 128 * 4;  // 256 KB
    constexpr size_t OFF_ZB   = OFF_WT   + (size_t)1024 * 128 * 2;  // 8 MB
    constexpr size_t OFF_QKV  = OFF_ZB   + (size_t)4096 * 1024 * 2; // 24 MB
    constexpr size_t OFF_ATT  = OFF_QKV  + (size_t)4096 * 3072 * 2; // 8 MB
    constexpr size_t OFF_FFN1 = OFF_QKV;                            // 32 MB alias (qkv+att dead)
    constexpr size_t OFF_SCR  = OFF_ATT  + (size_t)4096 * 1024 * 2; // 8 MB
    constexpr size_t OFF_XBF  = OFF_SCR  + (size_t)4096 * 1024 * 2; // 1 MB
    constexpr size_t OFF_WOBS = OFF_XBF  + (size_t)524288 * 2;      // 256 KB
    constexpr size_t OFF_CVT  = OFF_WOBS + (size_t)131072 * 2;      // 8 MB (max weight slice)
    constexpr size_t OFF_BO   = OFF_CVT  + (size_t)4096 * 1024 * 2;
    constexpr size_t OFF_B1   = OFF_BO   + 8192 * 2;
    constexpr size_t OFF_B2   = OFF_B1   + 32768 * 2;
    constexpr size_t OFF_L1G  = OFF_B2   + 8192 * 2;
    constexpr size_t OFF_L1B  = OFF_L1G  + 8192 * 2;
    constexpr size_t OFF_L2G  = OFF_L1B  + 8192 * 2;
    constexpr size_t OFF_L2B  = OFF_L2G  + 8192 * 2;
    constexpr size_t OFF_FLAG = OFF_L2B  + 8192 * 2;                // 4 B

    float* G             = (float*)(ws + OFF_G);
    float* Gi            = (float*)(ws + OFF_GI);
    float* y             = (float*)(ws + OFF_Y);
    unsigned short* WT   = (unsigned short*)(ws + OFF_WT);
    unsigned short* zb   = (unsigned short*)(ws + OFF_ZB);
    unsigned short* qkvb = (unsigned short*)(ws + OFF_QKV);
    unsigned short* attnb= (unsigned short*)(ws + OFF_ATT);
    unsigned short* ffn1 = (unsigned short*)(ws + OFF_FFN1);
    unsigned short* scr  = (unsigned short*)(ws + OFF_SCR);
    unsigned short* xbf  = (unsigned short*)(ws + OFF_XBF);
    unsigned short* wobs = (unsigned short*)(ws + OFF_WOBS);
    unsigned short* cvtb = (unsigned short*)(ws + OFF_CVT);
    unsigned short* boB  = (unsigned short*)(ws + OFF_BO);
    unsigned short* b1B  = (unsigned short*)(ws + OFF_B1);
    unsigned short* b2B  = (unsigned short*)(ws + OFF_B2);
    unsigned short* l1g  = (unsigned short*)(ws + OFF_L1G);
    unsigned short* l1b  = (unsigned short*)(ws + OFF_L1B);
    unsigned short* l2g  = (unsigned short*)(ws + OFF_L2G);
    unsigned short* l2b  = (unsigned short*)(ws + OFF_L2B);
    int* flag            = (int*)(ws + OFF_FLAG);

    sniff_dtype<<<1, 256, 0, stream>>>((const unsigned int*)Wobs_raw, flag);

    auto cvt = [&](const void* src, size_t off, unsigned short* dst, int n) {
        cvt_in<<<(n + 1023) / 1024, 256, 0, stream>>>(src, off, dst, n, flag);
    };

    // small persistent conversions
    cvt(x_raw, 0, xbf, 524288);
    cvt(Wobs_raw, 0, wobs, 131072);
    cvt(bo_raw, 0, boB, 8192);
    cvt(b1_raw, 0, b1B, 32768);
    cvt(b2_raw, 0, b2B, 8192);
    cvt(ln1g_raw, 0, l1g, 8192);
    cvt(ln1b_raw, 0, l1b, 8192);
    cvt(ln2g_raw, 0, l2g, 8192);
    cvt(ln2b_raw, 0, l2b, 8192);

    transpose_wobs<<<512, 256, 0, stream>>>(wobs, WT);
    compute_G<<<128, 128, 0, stream>>>(WT, G);
    sweep_inv<<<1, 1024, 0, stream>>>(G, Gi);
    embed_y<<<4096, 128, 0, stream>>>(xbf, Gi, y);
    embed_z<<<4096, 256, 0, stream>>>(y, wobs, zb);

    for (int l = 0; l < 8; ++l) {
        // QKV
        cvt(Wqkv_raw, (size_t)l * 3072 * 1024, cvtb, 3072 * 1024);
        gemm_bt<<<dim3(24, 32), 256, 0, stream>>>(zb, cvtb, nullptr, qkvb, 4096, 3072, 1024, 0);
        attn_kernel<<<dim3(32, 128), 256, 0, stream>>>(qkvb, attnb);
        // Wo
        cvt(Wo_raw, (size_t)l * 1024 * 1024, cvtb, 1024 * 1024);
        gemm_bt<<<dim3(8, 32), 256, 0, stream>>>(attnb, cvtb, boB + (size_t)l * 1024, scr, 4096, 1024, 1024, 0);
        resid_ln<<<4096, 256, 0, stream>>>(zb, scr, l1g + (size_t)l * 1024, l1b + (size_t)l * 1024, zb);
        // FFN
        cvt(W1_raw, (size_t)l * 4096 * 1024, cvtb, 4096 * 1024);
        gemm_bt<<<dim3(32, 32), 256, 0, stream>>>(zb, cvtb, b1B + (size_t)l * 4096, ffn1, 4096, 4096, 1024, 1);
        cvt(W2_raw, (size_t)l * 1024 * 4096, cvtb, 1024 * 4096);
        gemm_bt<<<dim3(8, 32), 256, 0, stream>>>(ffn1, cvtb, b2B + (size_t)l * 1024, scr, 4096, 1024, 4096, 0);
        resid_ln<<<4096, 256, 0, stream>>>(zb, scr, l2g + (size_t)l * 1024, l2b + (size_t)l * 1024, zb);
    }

    // final projection into scr (bf16), then dtype-correct output write
    gemm_bt<<<dim3(1, 32), 256, 0, stream>>>(zb, wobs, nullptr, scr, 4096, 128, 1024, 0);
    write_out<<<(out_size + 255) / 256, 256, 0, stream>>>(scr, d_out, out_size, flag);
}

// Round 3
// 2809.708 us; speedup vs baseline: 1.7639x; 1.5162x over previous
//
#include <hip/hip_runtime.h>
#include <math.h>

typedef __attribute__((ext_vector_type(8))) short short8;
typedef __attribute__((ext_vector_type(4))) float f32x4;

__device__ __forceinline__ float bf2f(unsigned short u) {
    union { unsigned int i; float f; } x; x.i = ((unsigned int)u) << 16; return x.f;
}
__device__ __forceinline__ unsigned short f2bf(float f) {
    union { float f; unsigned int i; } x; x.f = f;
    unsigned int i = x.i;
    return (unsigned short)((i + 0x7fffu + ((i >> 16) & 1u)) >> 16);
}

// ---------------------------------------------------------------------------
// dtype sniffer: decides whether inputs are bf16-packed or fp32.
// ---------------------------------------------------------------------------
__global__ __launch_bounds__(256) void sniff_dtype(const unsigned int* __restrict__ w,
                                                   int* __restrict__ flag)
{
    __shared__ int red[4];
    int t = threadIdx.x;
    int hits = 0;
    for (int u = 0; u < 16; ++u) {
        unsigned int word = w[t * 16 + u];
        unsigned int ex = (word >> 7) & 0xFFu;   // exponent field of LOW short as bf16
        if (ex >= 100u && ex <= 126u) ++hits;
    }
#pragma unroll
    for (int off = 32; off >= 1; off >>= 1) hits += __shfl_xor(hits, off, 64);
    if ((t & 63) == 0) red[t >> 6] = hits;
    __syncthreads();
    if (t == 0) flag[0] = ((red[0] + red[1] + red[2] + red[3]) > 2048) ? 1 : 0;
}

// convert n elements of src (starting at element elem_off) to bf16 in dst
__global__ __launch_bounds__(256) void cvt_in(const void* __restrict__ src, size_t elem_off,
                                              unsigned short* __restrict__ dst, int n,
                                              const int* __restrict__ flag)
{
    int i = (blockIdx.x * 256 + threadIdx.x) * 4;
    int m = *flag;
    if (i + 3 < n) {
        if (m) {
            const unsigned short* s = (const unsigned short*)src + elem_off + i;
            *(ushort4*)(dst + i) = *(const ushort4*)s;
        } else {
            const float* s = (const float*)src + elem_off + i;
            float4 v = *(const float4*)s;
            ushort4 o; o.x = f2bf(v.x); o.y = f2bf(v.y); o.z = f2bf(v.z); o.w = f2bf(v.w);
            *(ushort4*)(dst + i) = o;
        }
    } else {
        for (int u = i; u < n; ++u) {
            if (m) dst[u] = ((const unsigned short*)src)[elem_off + u];
            else   dst[u] = f2bf(((const float*)src)[elem_off + u]);
        }
    }
}

// write output: bf16 result -> d_out in the detected dtype; scrub non-finite to 1000
__global__ __launch_bounds__(256) void write_out(const unsigned short* __restrict__ src,
                                                 void* __restrict__ dst, int n,
                                                 const int* __restrict__ flag)
{
    int i = blockIdx.x * 256 + threadIdx.x;
    if (i >= n) return;
    unsigned short u = src[i];
    if ((u & 0x7F80u) == 0x7F80u) u = 0x447Au;   // sentinel 1000.0 for NaN/Inf
    if (*flag) ((unsigned short*)dst)[i] = u;
    else       ((float*)dst)[i] = bf2f(u);
}

// ---------------------------------------------------------------------------
// GEMM: C[M,N] = A[M,K] @ B[N,K]^T (+bias, optional ReLU), bf16 in/out, fp32 acc
// ---------------------------------------------------------------------------
__global__ __launch_bounds__(256) void gemm_bt(
    const unsigned short* __restrict__ A,
    const unsigned short* __restrict__ B,
    const unsigned short* __restrict__ bias,
    unsigned short* __restrict__ C,
    int M, int N, int K, int relu)
{
    __shared__ __align__(16) unsigned short As[128 * 32];
    __shared__ __align__(16) unsigned short Bs[128 * 32];
    const int t = threadIdx.x;
    const int lane = t & 63;
    const int w = t >> 6;
    const int la = lane & 15;
    const int quad = lane >> 4;
    const int m0 = blockIdx.y * 128;
    const int n0 = blockIdx.x * 128;
    const int wm = (w >> 1) * 64;
    const int wn = (w & 1) * 64;
    f32x4 acc[4][4];
#pragma unroll
    for (int i = 0; i < 4; ++i)
#pragma unroll
        for (int j = 0; j < 4; ++j) acc[i][j] = (f32x4){0.f, 0.f, 0.f, 0.f};

    const int row0 = t >> 2, seg0 = t & 3;
    const unsigned short* Ap = A + (size_t)(m0 + row0) * K + seg0 * 8;
    const unsigned short* Bp = B + (size_t)(n0 + row0) * K + seg0 * 8;

    for (int kt = 0; kt < K; kt += 32) {
        __syncthreads();
        {
            int4 va0 = *(const int4*)(Ap + kt);
            int4 va1 = *(const int4*)(Ap + (size_t)64 * K + kt);
            int4 vb0 = *(const int4*)(Bp + kt);
            int4 vb1 = *(const int4*)(Bp + (size_t)64 * K + kt);
            *(int4*)(As + row0 * 32 + seg0 * 8) = va0;
            *(int4*)(As + (row0 + 64) * 32 + seg0 * 8) = va1;
            *(int4*)(Bs + row0 * 32 + seg0 * 8) = vb0;
            *(int4*)(Bs + (row0 + 64) * 32 + seg0 * 8) = vb1;
        }
        __syncthreads();
        short8 af[4], bfr[4];
#pragma unroll
        for (int i = 0; i < 4; ++i)
            af[i] = *(const short8*)(As + (wm + i * 16 + la) * 32 + quad * 8);
#pragma unroll
        for (int j = 0; j < 4; ++j)
            bfr[j] = *(const short8*)(Bs + (wn + j * 16 + la) * 32 + quad * 8);
#pragma unroll
        for (int i = 0; i < 4; ++i)
#pragma unroll
            for (int j = 0; j < 4; ++j)
                acc[i][j] = __builtin_amdgcn_mfma_f32_16x16x32_bf16(af[i], bfr[j], acc[i][j], 0, 0, 0);
    }

#pragma unroll
    for (int j = 0; j < 4; ++j) {
        int n = n0 + wn + j * 16 + la;
        float bv = bias ? bf2f(bias[n]) : 0.0f;
#pragma unroll
        for (int i = 0; i < 4; ++i) {
#pragma unroll
            for (int r = 0; r < 4; ++r) {
                int m = m0 + wm + i * 16 + quad * 4 + r;
                float v = acc[i][j][r] + bv;
                if (relu) v = fmaxf(v, 0.0f);
                C[(size_t)m * N + n] = f2bf(v);
            }
        }
    }
}

// ---------------------------------------------------------------------------
// Fused flash attention: one block = 64 queries (4 waves x 16q) of one (b,h).
// Swapped QK^T (mfma(K,Q) -> S^T): lane holds full score slice of ONE q-row
// -> softmax is register-local + 2 shfl_xor. Online max/sum.
// Hardened vs v2: Q fragments loaded DIRECTLY from global (no LDS staging, no
// buffer reuse), dedicated Ps buffer, and a full __syncthreads() between the
// P ds_writes and PV ds_reads (replaces inline-asm lgkmcnt sync — rule #18).
// ---------------------------------------------------------------------------
__global__ __launch_bounds__(256, 3) void attn_kernel(
    const unsigned short* __restrict__ qkv,
    unsigned short* __restrict__ attn_out)
{
    // Ks: K chunk [128][72]  (stride 72 shorts = 144B, 16B-aligned)
    // Vt: V^T chunk [64][136] (stride 136 shorts = 272B, 16B-aligned)
    // Ps: per-wave P strips [16][136]
    __shared__ __align__(16) unsigned short Ks[128 * 72];
    __shared__ __align__(16) unsigned short Vt[64 * 136];
    __shared__ __align__(16) unsigned short Ps[4 * 16 * 136];

    const int t = threadIdx.x;
    const int lane = t & 63;
    const int w = t >> 6;
    const int la = lane & 15;
    const int quad = lane >> 4;

    // XCD-bijective remap: all 8 q-tiles of one (b,h) land on the same XCD
    // (round-robin bid%8 assumption; perf-only, bijective for 1024 blocks).
    int bid = blockIdx.y * 8 + blockIdx.x;
    int xcd = bid & 7, idx = bid >> 3;
    int bh = ((idx & 15) << 3) | xcd;
    int qt = idx >> 4;
    const int b = bh >> 4, h = bh & 15;
    const int q0 = qt * 64;
    const size_t rowbase = (size_t)b * 512;
    const int qoff = h * 192, koff = h * 192 + 64, voff = h * 192 + 128;

    // Q fragments straight from global: lane (la,quad) holds Q[q=w*16+la][dc*32+quad*8 ..+7]
    short8 aq[2];
#pragma unroll
    for (int dc = 0; dc < 2; ++dc)
        aq[dc] = *(const short8*)(qkv + (rowbase + q0 + w * 16 + la) * 3072 + qoff + dc * 32 + quad * 8);

    unsigned short* PsW = Ps + w * (16 * 136);

    f32x4 oacc[4];
#pragma unroll
    for (int dt2 = 0; dt2 < 4; ++dt2) oacc[dt2] = (f32x4){0.f, 0.f, 0.f, 0.f};
    float mrun = -1e30f, lrun = 0.f;

#pragma unroll 1
    for (int c = 0; c < 4; ++c) {
        __syncthreads();   // prev chunk's Ks/Vt reads complete before restage
        // stage K chunk: [128][64] -> Ks stride 72, b128 writes
#pragma unroll
        for (int it = 0; it < 4; ++it) {
            int idx2 = it * 256 + t;
            int kk = idx2 >> 3, d8 = idx2 & 7;
            int4 v = *(const int4*)(qkv + (rowbase + c * 128 + kk) * 3072 + koff + d8 * 8);
            *(int4*)(Ks + kk * 72 + d8 * 8) = v;
        }
        // stage V chunk transposed: thread loads 4 k-rows x 8 d, writes 8 b64
        {
            int d8 = t & 7, kq = t >> 3;      // kq 0..31
            int k0 = kq * 4;
            const unsigned short* vb = qkv + (rowbase + c * 128 + k0) * 3072 + voff + d8 * 8;
            union { int4 q; unsigned short s[8]; } a0, a1, a2, a3;
            a0.q = *(const int4*)(vb);
            a1.q = *(const int4*)(vb + 3072);
            a2.q = *(const int4*)(vb + 6144);
            a3.q = *(const int4*)(vb + 9216);
#pragma unroll
            for (int u = 0; u < 8; ++u) {
                ushort4 o; o.x = a0.s[u]; o.y = a1.s[u]; o.z = a2.s[u]; o.w = a3.s[u];
                *(ushort4*)(Vt + (d8 * 8 + u) * 136 + k0) = o;
            }
        }
        __syncthreads();

        // QK^T swapped: S^T[k][q] tiles; A = K rows, B = this wave's Q rows
        f32x4 st[8];
#pragma unroll
        for (int kt2 = 0; kt2 < 8; ++kt2) {
            f32x4 acc = (f32x4){0.f, 0.f, 0.f, 0.f};
#pragma unroll
            for (int dc = 0; dc < 2; ++dc) {
                short8 af = *(const short8*)(Ks + (kt2 * 16 + la) * 72 + dc * 32 + quad * 8);
                acc = __builtin_amdgcn_mfma_f32_16x16x32_bf16(af, aq[dc], acc, 0, 0, 0);
            }
            st[kt2] = acc;
        }
        // lane holds scores of q-row (q = la), keys kt2*16 + quad*4 + r
        float pmax = -1e30f;
#pragma unroll
        for (int kt2 = 0; kt2 < 8; ++kt2) {
#pragma unroll
            for (int r = 0; r < 4; ++r) {
                st[kt2][r] *= 0.125f;
                pmax = fmaxf(pmax, st[kt2][r]);
            }
        }
        pmax = fmaxf(pmax, __shfl_xor(pmax, 16, 64));
        pmax = fmaxf(pmax, __shfl_xor(pmax, 32, 64));
        float mnew = fmaxf(mrun, pmax);
        float f = __expf(mrun - mnew);
        mrun = mnew;
        float psum = 0.f;
#pragma unroll
        for (int kt2 = 0; kt2 < 8; ++kt2) {
            float e0 = __expf(st[kt2][0] - mrun);
            float e1 = __expf(st[kt2][1] - mrun);
            float e2 = __expf(st[kt2][2] - mrun);
            float e3 = __expf(st[kt2][3] - mrun);
            psum += (e0 + e1) + (e2 + e3);
            ushort4 o; o.x = f2bf(e0); o.y = f2bf(e1); o.z = f2bf(e2); o.w = f2bf(e3);
            *(ushort4*)(PsW + la * 136 + kt2 * 16 + quad * 4) = o;   // P[q=la][k]
        }
        psum += __shfl_xor(psum, 16, 64);
        psum += __shfl_xor(psum, 32, 64);
        lrun = lrun * f + psum;
        // rescale O accumulator: f is per q-row; oacc rows are q = quad*4+r
        float fr[4];
#pragma unroll
        for (int r = 0; r < 4; ++r) fr[r] = __shfl(f, quad * 4 + r, 64);
#pragma unroll
        for (int dt2 = 0; dt2 < 4; ++dt2)
#pragma unroll
            for (int r = 0; r < 4; ++r) oacc[dt2][r] *= fr[r];
        // full barrier: all P writes visible before PV fragment reads
        __syncthreads();
        // PV: A = P rows (la), B = Vt rows (d = dt2*16+la)
#pragma unroll
        for (int ks = 0; ks < 4; ++ks) {
            short8 pa = *(const short8*)(PsW + la * 136 + ks * 32 + quad * 8);
#pragma unroll
            for (int dt2 = 0; dt2 < 4; ++dt2) {
                short8 bv = *(const short8*)(Vt + (dt2 * 16 + la) * 136 + ks * 32 + quad * 8);
                oacc[dt2] = __builtin_amdgcn_mfma_f32_16x16x32_bf16(pa, bv, oacc[dt2], 0, 0, 0);
            }
        }
    }

    // epilogue: divide by softmax sum, write out
    float linv = 1.0f / lrun;
    float lr[4];
#pragma unroll
    for (int r = 0; r < 4; ++r) lr[r] = __shfl(linv, quad * 4 + r, 64);
#pragma unroll
    for (int dt2 = 0; dt2 < 4; ++dt2) {
        int d = h * 64 + dt2 * 16 + la;
#pragma unroll
        for (int r = 0; r < 4; ++r) {
            int q = q0 + w * 16 + quad * 4 + r;
            attn_out[(rowbase + q) * 1024 + d] = f2bf(oacc[dt2][r] * lr[r]);
        }
    }
}

// ---------------------------------------------------------------------------
// residual + LayerNorm, bf16 in/out (in-place on z), fp32 internals
// ---------------------------------------------------------------------------
__global__ __launch_bounds__(256) void resid_ln(
    const unsigned short* __restrict__ z_in, const unsigned short* __restrict__ br,
    const unsigned short* __restrict__ g, const unsigned short* __restrict__ bb,
    unsigned short* __restrict__ z_out)
{
    __shared__ float red[4];
    const int m = blockIdx.x, t = threadIdx.x;
    float v[4];
#pragma unroll
    for (int u = 0; u < 4; ++u) {
        int e = t + u * 256;
        v[u] = bf2f(z_in[(size_t)m * 1024 + e]) + bf2f(br[(size_t)m * 1024 + e]);
    }
    float s = v[0] + v[1] + v[2] + v[3];
#pragma unroll
    for (int off = 32; off >= 1; off >>= 1) s += __shfl_xor(s, off, 64);
    if ((t & 63) == 0) red[t >> 6] = s;
    __syncthreads();
    float mean = (red[0] + red[1] + red[2] + red[3]) * (1.0f / 1024.0f);
    __syncthreads();
    float q = 0.f;
#pragma unroll
    for (int u = 0; u < 4; ++u) { float d = v[u] - mean; q += d * d; }
#pragma unroll
    for (int off = 32; off >= 1; off >>= 1) q += __shfl_xor(q, off, 64);
    if ((t & 63) == 0) red[t >> 6] = q;
    __syncthreads();
    float var = (red[0] + red[1] + red[2] + red[3]) * (1.0f / 1024.0f);
    float inv = rsqrtf(var + 1e-5f);
#pragma unroll
    for (int u = 0; u < 4; ++u) {
        int e = t + u * 256;
        float o = (v[u] - mean) * inv * bf2f(g[e]) + bf2f(bb[e]);
        z_out[(size_t)m * 1024 + e] = f2bf(o);
    }
}

// ---------------------------------------------------------------------------
// pinv pieces (inputs already converted to bf16)
// ---------------------------------------------------------------------------
__global__ void transpose_wobs(const unsigned short* __restrict__ W, unsigned short* __restrict__ WT)
{
    int idx = blockIdx.x * 256 + threadIdx.x;     // 131072 total
    int o = idx >> 10, e = idx & 1023;
    WT[e * 128 + o] = W[idx];
}

__global__ void compute_G(const unsigned short* __restrict__ WT, float* __restrict__ G)
{
    int i = blockIdx.x, j = threadIdx.x;          // 128 x 128
    float s = 0.f;
    for (int e = 0; e < 1024; ++e)
        s += bf2f(WT[e * 128 + i]) * bf2f(WT[e * 128 + j]);
    G[i * 128 + j] = s;
}

// sweep operator: sweeping all pivots of SPD A in place yields -A^{-1}
// Thread->element map: column j = t&127 (stride-1 across a wave's lanes ->
// conflict-free LDS), rows i = (t>>7) + 8u. Col-k snapshot reads are
// wave-uniform (broadcast, free).
__global__ __launch_bounds__(1024) void sweep_inv(const float* __restrict__ G, float* __restrict__ Gi)
{
    __shared__ float M[128 * 128];                // 64 KB
    const int t = threadIdx.x;
    for (int i = t; i < 16384; i += 1024) M[i] = G[i];
    __syncthreads();
    const int j = t & 127;                        // column (consecutive within wave)
    const int ib = t >> 7;                        // row base 0..7 (wave-uniform)
    for (int k = 0; k < 128; ++k) {
        float d = M[k * 128 + k];                 // broadcast
        float p = 1.0f / d;
        float rj = M[k * 128 + j];                // row-k snapshot, conflict-free
        float cv[16];
#pragma unroll
        for (int u = 0; u < 16; ++u)
            cv[u] = M[(ib + u * 8) * 128 + k];    // col-k snapshot, broadcast
        __syncthreads();
#pragma unroll
        for (int u = 0; u < 16; ++u) {
            int i = ib + u * 8;
            float nv;
            if (i == k && j == k)      nv = -p;
            else if (i == k)           nv = rj * p;
            else if (j == k)           nv = cv[u] * p;
            else                       nv = M[i * 128 + j] - cv[u] * rj * p;
            M[i * 128 + j] = nv;                  // conflict-free
        }
        __syncthreads();
    }
    for (int n = t; n < 16384; n += 1024) Gi[n] = -M[n];
}

__global__ void embed_y(const unsigned short* __restrict__ x, const float* __restrict__ Gi,
                        float* __restrict__ y)
{
    int m = blockIdx.x, t = threadIdx.x;  // 128 threads
    float s = 0.f;
    for (int o = 0; o < 128; ++o)
        s += bf2f(x[(size_t)m * 128 + o]) * Gi[o * 128 + t];
    y[(size_t)m * 128 + t] = s;
}

__global__ __launch_bounds__(256) void embed_z(const float* __restrict__ y,
                                               const unsigned short* __restrict__ Wobs,
                                               unsigned short* __restrict__ zb)
{
    int m = blockIdx.x, t = threadIdx.x;
    int s = m & 511;
    float accv[4] = {0.f, 0.f, 0.f, 0.f};
    for (int o = 0; o < 128; ++o) {
        float yv = y[(size_t)m * 128 + o];
#pragma unroll
        for (int u = 0; u < 4; ++u) {
            int e = t + u * 256;
            accv[u] += yv * bf2f(Wobs[o * 1024 + e]);
        }
    }
#pragma unroll
    for (int u = 0; u < 4; ++u) {
        int e = t + u * 256;
        float freq = __expf(-0.008994473019508f * (float)(e & ~1));
        float ang = (float)s * freq;
        float pe = (e & 1) ? cosf(ang) : sinf(ang);
        float v = accv[u] + pe;
        zb[(size_t)m * 1024 + e] = f2bf(v);
    }
}

// ---------------------------------------------------------------------------
extern "C" void kernel_launch(void* const* d_in, const int* in_sizes, int n_in,
                              void* d_out, int out_size, void* d_ws, size_t ws_size,
                              hipStream_t stream)
{
    const void* x_raw     = d_in[0];
    const void* Wobs_raw  = d_in[1];
    const void* Wqkv_raw  = d_in[2];
    const void* Wo_raw    = d_in[3];
    const void* bo_raw    = d_in[4];
    const void* ln1g_raw  = d_in[5];
    const void* ln1b_raw  = d_in[6];
    const void* W1_raw    = d_in[7];
    const void* b1_raw    = d_in[8];
    const void* W2_raw    = d_in[9];
    const void* b2_raw    = d_in[10];
    const void* ln2g_raw  = d_in[11];
    const void* ln2b_raw  = d_in[12];

    char* ws = (char*)d_ws;
    constexpr size_t OFF_G    = 0;                                  // 64 KB
    constexpr size_t OFF_GI   = OFF_G    + 65536;                   // 64 KB
    constexpr size_t OFF_Y    = OFF_GI   + 65536;                   // 2 MB fp32
    constexpr size_t OFF_WT   = OFF_Y    + (size_t)4096 * 128 * 4;  // 256 KB
    constexpr size_t OFF_ZB   = OFF_WT   + (size_t)1024 * 128 * 2;  // 8 MB
    constexpr size_t OFF_QKV  = OFF_ZB   + (size_t)4096 * 1024 * 2; // 24 MB
    constexpr size_t OFF_ATT  = OFF_QKV  + (size_t)4096 * 3072 * 2; // 8 MB
    constexpr size_t OFF_FFN1 = OFF_QKV;                            // 32 MB alias (qkv+att dead)
    constexpr size_t OFF_SCR  = OFF_ATT  + (size_t)4096 * 1024 * 2; // 8 MB
    constexpr size_t OFF_XBF  = OFF_SCR  + (size_t)4096 * 1024 * 2; // 1 MB
    constexpr size_t OFF_WOBS = OFF_XBF  + (size_t)524288 * 2;      // 256 KB
    constexpr size_t OFF_CVT  = OFF_WOBS + (size_t)131072 * 2;      // 8 MB (max weight slice)
    constexpr size_t OFF_BO   = OFF_CVT  + (size_t)4096 * 1024 * 2;
    constexpr size_t OFF_B1   = OFF_BO   + 8192 * 2;
    constexpr size_t OFF_B2   = OFF_B1   + 32768 * 2;
    constexpr size_t OFF_L1G  = OFF_B2   + 8192 * 2;
    constexpr size_t OFF_L1B  = OFF_L1G  + 8192 * 2;
    constexpr size_t OFF_L2G  = OFF_L1B  + 8192 * 2;
    constexpr size_t OFF_L2B  = OFF_L2G  + 8192 * 2;
    constexpr size_t OFF_FLAG = OFF_L2B  + 8192 * 2;                // 4 B

    float* G             = (float*)(ws + OFF_G);
    float* Gi            = (float*)(ws + OFF_GI);
    float* y             = (float*)(ws + OFF_Y);
    unsigned short* WT   = (unsigned short*)(ws + OFF_WT);
    unsigned short* zb   = (unsigned short*)(ws + OFF_ZB);
    unsigned short* qkvb = (unsigned short*)(ws + OFF_QKV);
    unsigned short* attnb= (unsigned short*)(ws + OFF_ATT);
    unsigned short* ffn1 = (unsigned short*)(ws + OFF_FFN1);
    unsigned short* scr  = (unsigned short*)(ws + OFF_SCR);
    unsigned short* xbf  = (unsigned short*)(ws + OFF_XBF);
    unsigned short* wobs = (unsigned short*)(ws + OFF_WOBS);
    unsigned short* cvtb = (unsigned short*)(ws + OFF_CVT);
    unsigned short* boB  = (unsigned short*)(ws + OFF_BO);
    unsigned short* b1B  = (unsigned short*)(ws + OFF_B1);
    unsigned short* b2B  = (unsigned short*)(ws + OFF_B2);
    unsigned short* l1g  = (unsigned short*)(ws + OFF_L1G);
    unsigned short* l1b  = (unsigned short*)(ws + OFF_L1B);
    unsigned short* l2g  = (unsigned short*)(ws + OFF_L2G);
    unsigned short* l2b  = (unsigned short*)(ws + OFF_L2B);
    int* flag            = (int*)(ws + OFF_FLAG);

    sniff_dtype<<<1, 256, 0, stream>>>((const unsigned int*)Wobs_raw, flag);

    auto cvt = [&](const void* src, size_t off, unsigned short* dst, int n) {
        cvt_in<<<(n + 1023) / 1024, 256, 0, stream>>>(src, off, dst, n, flag);
    };

    // small persistent conversions
    cvt(x_raw, 0, xbf, 524288);
    cvt(Wobs_raw, 0, wobs, 131072);
    cvt(bo_raw, 0, boB, 8192);
    cvt(b1_raw, 0, b1B, 32768);
    cvt(b2_raw, 0, b2B, 8192);
    cvt(ln1g_raw, 0, l1g, 8192);
    cvt(ln1b_raw, 0, l1b, 8192);
    cvt(ln2g_raw, 0, l2g, 8192);
    cvt(ln2b_raw, 0, l2b, 8192);

    transpose_wobs<<<512, 256, 0, stream>>>(wobs, WT);
    compute_G<<<128, 128, 0, stream>>>(WT, G);
    sweep_inv<<<1, 1024, 0, stream>>>(G, Gi);
    embed_y<<<4096, 128, 0, stream>>>(xbf, Gi, y);
    embed_z<<<4096, 256, 0, stream>>>(y, wobs, zb);

    for (int l = 0; l < 8; ++l) {
        // QKV
        cvt(Wqkv_raw, (size_t)l * 3072 * 1024, cvtb, 3072 * 1024);
        gemm_bt<<<dim3(24, 32), 256, 0, stream>>>(zb, cvtb, nullptr, qkvb, 4096, 3072, 1024, 0);
        attn_kernel<<<dim3(8, 128), 256, 0, stream>>>(qkvb, attnb);
        // Wo
        cvt(Wo_raw, (size_t)l * 1024 * 1024, cvtb, 1024 * 1024);
        gemm_bt<<<dim3(8, 32), 256, 0, stream>>>(attnb, cvtb, boB + (size_t)l * 1024, scr, 4096, 1024, 1024, 0);
        resid_ln<<<4096, 256, 0, stream>>>(zb, scr, l1g + (size_t)l * 1024, l1b + (size_t)l * 1024, zb);
        // FFN
        cvt(W1_raw, (size_t)l * 4096 * 1024, cvtb, 4096 * 1024);
        gemm_bt<<<dim3(32, 32), 256, 0, stream>>>(zb, cvtb, b1B + (size_t)l * 4096, ffn1, 4096, 4096, 1024, 1);
        cvt(W2_raw, (size_t)l * 1024 * 4096, cvtb, 1024 * 4096);
        gemm_bt<<<dim3(8, 32), 256, 0, stream>>>(ffn1, cvtb, b2B + (size_t)l * 1024, scr, 4096, 1024, 4096, 0);
        resid_ln<<<4096, 256, 0, stream>>>(zb, scr, l2g + (size_t)l * 1024, l2b + (size_t)l * 1024, zb);
    }

    // final projection into scr (bf16), then dtype-correct output write
    gemm_bt<<<dim3(1, 32), 256, 0, stream>>>(zb, wobs, nullptr, scr, 4096, 128, 1024, 0);
    write_out<<<(out_size + 255) / 256, 256, 0, stream>>>(scr, d_out, out_size, flag);
}

// Round 6
// 2702.284 us; speedup vs baseline: 1.8340x; 1.0398x over previous
//
#include <hip/hip_runtime.h>
#include <math.h>

typedef __attribute__((ext_vector_type(8))) short short8;
typedef __attribute__((ext_vector_type(4))) float f32x4;

__device__ __forceinline__ float bf2f(unsigned short u) {
    union { unsigned int i; float f; } x; x.i = ((unsigned int)u) << 16; return x.f;
}
__device__ __forceinline__ unsigned short f2bf(float f) {
    union { float f; unsigned int i; } x; x.f = f;
    unsigned int i = x.i;
    return (unsigned short)((i + 0x7fffu + ((i >> 16) & 1u)) >> 16);
}

// async global->LDS, 16B per lane. LDS dest must be wave-uniform base + lane*16
// (our staging layouts are linear in t, so this holds).
__device__ __forceinline__ void gload16(const unsigned short* g, unsigned short* l)
{
    __builtin_amdgcn_global_load_lds(
        (__attribute__((address_space(1))) void*)(g),
        (__attribute__((address_space(3))) void*)(l),
        16, 0, 0);
}

// ---------------------------------------------------------------------------
// dtype sniffer: decides whether inputs are bf16-packed or fp32.
// ---------------------------------------------------------------------------
__global__ __launch_bounds__(256) void sniff_dtype(const unsigned int* __restrict__ w,
                                                   int* __restrict__ flag)
{
    __shared__ int red[4];
    int t = threadIdx.x;
    int hits = 0;
    for (int u = 0; u < 16; ++u) {
        unsigned int word = w[t * 16 + u];
        unsigned int ex = (word >> 7) & 0xFFu;   // exponent field of LOW short as bf16
        if (ex >= 100u && ex <= 126u) ++hits;
    }
#pragma unroll
    for (int off = 32; off >= 1; off >>= 1) hits += __shfl_xor(hits, off, 64);
    if ((t & 63) == 0) red[t >> 6] = hits;
    __syncthreads();
    if (t == 0) flag[0] = ((red[0] + red[1] + red[2] + red[3]) > 2048) ? 1 : 0;
}

// convert n elements of src (starting at element elem_off) to bf16 in dst
__global__ __launch_bounds__(256) void cvt_in(const void* __restrict__ src, size_t elem_off,
                                              unsigned short* __restrict__ dst, int n,
                                              const int* __restrict__ flag)
{
    int i = (blockIdx.x * 256 + threadIdx.x) * 4;
    int m = *flag;
    if (i + 3 < n) {
        if (m) {
            const unsigned short* s = (const unsigned short*)src + elem_off + i;
            *(ushort4*)(dst + i) = *(const ushort4*)s;
        } else {
            const float* s = (const float*)src + elem_off + i;
            float4 v = *(const float4*)s;
            ushort4 o; o.x = f2bf(v.x); o.y = f2bf(v.y); o.z = f2bf(v.z); o.w = f2bf(v.w);
            *(ushort4*)(dst + i) = o;
        }
    } else {
        for (int u = i; u < n; ++u) {
            if (m) dst[u] = ((const unsigned short*)src)[elem_off + u];
            else   dst[u] = f2bf(((const float*)src)[elem_off + u]);
        }
    }
}

// write output: bf16 result -> d_out in the detected dtype; scrub non-finite to 1000
__global__ __launch_bounds__(256) void write_out(const unsigned short* __restrict__ src,
                                                 void* __restrict__ dst, int n,
                                                 const int* __restrict__ flag)
{
    int i = blockIdx.x * 256 + threadIdx.x;
    if (i >= n) return;
    unsigned short u = src[i];
    if ((u & 0x7F80u) == 0x7F80u) u = 0x447Au;   // sentinel 1000.0 for NaN/Inf
    if (*flag) ((unsigned short*)dst)[i] = u;
    else       ((float*)dst)[i] = bf2f(u);
}

// ---------------------------------------------------------------------------
// GEMM: C[M,N] = A[M,K] @ B[N,K]^T (+bias, optional ReLU), bf16 in/out, fp32 acc
// m97 structure: async global_load_lds dwordx4 staging (no VGPR round-trip).
// ---------------------------------------------------------------------------
__global__ __launch_bounds__(256) void gemm_bt(
    const unsigned short* __restrict__ A,
    const unsigned short* __restrict__ B,
    const unsigned short* __restrict__ bias,
    unsigned short* __restrict__ C,
    int M, int N, int K, int relu)
{
    __shared__ __align__(16) unsigned short As[128 * 32];
    __shared__ __align__(16) unsigned short Bs[128 * 32];
    const int t = threadIdx.x;
    const int lane = t & 63;
    const int w = t >> 6;
    const int la = lane & 15;
    const int quad = lane >> 4;
    const int m0 = blockIdx.y * 128;
    const int n0 = blockIdx.x * 128;
    const int wm = (w >> 1) * 64;
    const int wn = (w & 1) * 64;
    f32x4 acc[4][4];
#pragma unroll
    for (int i = 0; i < 4; ++i)
#pragma unroll
        for (int j = 0; j < 4; ++j) acc[i][j] = (f32x4){0.f, 0.f, 0.f, 0.f};

    const int row0 = t >> 2, seg0 = t & 3;
    const unsigned short* Ap = A + (size_t)(m0 + row0) * K + seg0 * 8;
    const unsigned short* Bp = B + (size_t)(n0 + row0) * K + seg0 * 8;
    unsigned short* lA0 = As + row0 * 32 + seg0 * 8;          // = As + t*16B: linear in t
    unsigned short* lA1 = As + (row0 + 64) * 32 + seg0 * 8;
    unsigned short* lB0 = Bs + row0 * 32 + seg0 * 8;
    unsigned short* lB1 = Bs + (row0 + 64) * 32 + seg0 * 8;

    for (int kt = 0; kt < K; kt += 32) {
        __syncthreads();                 // prev MFMA ds_reads complete
        gload16(Ap + kt, lA0);
        gload16(Ap + (size_t)64 * K + kt, lA1);
        gload16(Bp + kt, lB0);
        gload16(Bp + (size_t)64 * K + kt, lB1);
        __syncthreads();                 // drains vmcnt: staged data visible
        short8 af[4], bfr[4];
#pragma unroll
        for (int i = 0; i < 4; ++i)
            af[i] = *(const short8*)(As + (wm + i * 16 + la) * 32 + quad * 8);
#pragma unroll
        for (int j = 0; j < 4; ++j)
            bfr[j] = *(const short8*)(Bs + (wn + j * 16 + la) * 32 + quad * 8);
#pragma unroll
        for (int i = 0; i < 4; ++i)
#pragma unroll
            for (int j = 0; j < 4; ++j)
                acc[i][j] = __builtin_amdgcn_mfma_f32_16x16x32_bf16(af[i], bfr[j], acc[i][j], 0, 0, 0);
    }

#pragma unroll
    for (int j = 0; j < 4; ++j) {
        int n = n0 + wn + j * 16 + la;
        float bv = bias ? bf2f(bias[n]) : 0.0f;
#pragma unroll
        for (int i = 0; i < 4; ++i) {
#pragma unroll
            for (int r = 0; r < 4; ++r) {
                int m = m0 + wm + i * 16 + quad * 4 + r;
                float v = acc[i][j][r] + bv;
                if (relu) v = fmaxf(v, 0.0f);
                C[(size_t)m * N + n] = f2bf(v);
            }
        }
    }
}

// ---------------------------------------------------------------------------
// Fused flash attention: one block = 64 queries (4 waves x 16q) of one (b,h).
// Swapped QK^T (mfma(K,Q) -> S^T): lane holds full score slice of ONE q-row
// -> softmax is register-local + 2 shfl_xor. Online max/sum.
// ---------------------------------------------------------------------------
__global__ __launch_bounds__(256, 3) void attn_kernel(
    const unsigned short* __restrict__ qkv,
    unsigned short* __restrict__ attn_out)
{
    // Ks: K chunk [128][72]  (stride 72 shorts = 144B, 16B-aligned)
    // Vt: V^T chunk [64][136] (stride 136 shorts = 272B, 16B-aligned)
    // Ps: per-wave P strips [16][136]
    __shared__ __align__(16) unsigned short Ks[128 * 72];
    __shared__ __align__(16) unsigned short Vt[64 * 136];
    __shared__ __align__(16) unsigned short Ps[4 * 16 * 136];

    const int t = threadIdx.x;
    const int lane = t & 63;
    const int w = t >> 6;
    const int la = lane & 15;
    const int quad = lane >> 4;

    // XCD-bijective remap: all 8 q-tiles of one (b,h) land on the same XCD
    int bid = blockIdx.y * 8 + blockIdx.x;
    int xcd = bid & 7, idx = bid >> 3;
    int bh = ((idx & 15) << 3) | xcd;
    int qt = idx >> 4;
    const int b = bh >> 4, h = bh & 15;
    const int q0 = qt * 64;
    const size_t rowbase = (size_t)b * 512;
    const int qoff = h * 192, koff = h * 192 + 64, voff = h * 192 + 128;

    // Q fragments straight from global
    short8 aq[2];
#pragma unroll
    for (int dc = 0; dc < 2; ++dc)
        aq[dc] = *(const short8*)(qkv + (rowbase + q0 + w * 16 + la) * 3072 + qoff + dc * 32 + quad * 8);

    unsigned short* PsW = Ps + w * (16 * 136);

    f32x4 oacc[4];
#pragma unroll
    for (int dt2 = 0; dt2 < 4; ++dt2) oacc[dt2] = (f32x4){0.f, 0.f, 0.f, 0.f};
    float mrun = -1e30f, lrun = 0.f;

#pragma unroll 1
    for (int c = 0; c < 4; ++c) {
        __syncthreads();   // prev chunk's Ks/Vt reads complete before restage
        // stage K chunk: [128][64] -> Ks stride 72, b128 writes
#pragma unroll
        for (int it = 0; it < 4; ++it) {
            int idx2 = it * 256 + t;
            int kk = idx2 >> 3, d8 = idx2 & 7;
            int4 v = *(const int4*)(qkv + (rowbase + c * 128 + kk) * 3072 + koff + d8 * 8);
            *(int4*)(Ks + kk * 72 + d8 * 8) = v;
        }
        // stage V chunk transposed: thread loads 4 k-rows x 8 d, writes 8 b64
        {
            int d8 = t & 7, kq = t >> 3;      // kq 0..31
            int k0 = kq * 4;
            const unsigned short* vb = qkv + (rowbase + c * 128 + k0) * 3072 + voff + d8 * 8;
            union { int4 q; unsigned short s[8]; } a0, a1, a2, a3;
            a0.q = *(const int4*)(vb);
            a1.q = *(const int4*)(vb + 3072);
            a2.q = *(const int4*)(vb + 6144);
            a3.q = *(const int4*)(vb + 9216);
#pragma unroll
            for (int u = 0; u < 8; ++u) {
                ushort4 o; o.x = a0.s[u]; o.y = a1.s[u]; o.z = a2.s[u]; o.w = a3.s[u];
                *(ushort4*)(Vt + (d8 * 8 + u) * 136 + k0) = o;
            }
        }
        __syncthreads();

        // QK^T swapped: S^T[k][q] tiles; A = K rows, B = this wave's Q rows
        f32x4 st[8];
#pragma unroll
        for (int kt2 = 0; kt2 < 8; ++kt2) {
            f32x4 acc = (f32x4){0.f, 0.f, 0.f, 0.f};
#pragma unroll
            for (int dc = 0; dc < 2; ++dc) {
                short8 af = *(const short8*)(Ks + (kt2 * 16 + la) * 72 + dc * 32 + quad * 8);
                acc = __builtin_amdgcn_mfma_f32_16x16x32_bf16(af, aq[dc], acc, 0, 0, 0);
            }
            st[kt2] = acc;
        }
        // lane holds scores of q-row (q = la), keys kt2*16 + quad*4 + r
        float pmax = -1e30f;
#pragma unroll
        for (int kt2 = 0; kt2 < 8; ++kt2) {
#pragma unroll
            for (int r = 0; r < 4; ++r) {
                st[kt2][r] *= 0.125f;
                pmax = fmaxf(pmax, st[kt2][r]);
            }
        }
        pmax = fmaxf(pmax, __shfl_xor(pmax, 16, 64));
        pmax = fmaxf(pmax, __shfl_xor(pmax, 32, 64));
        float mnew = fmaxf(mrun, pmax);
        float f = __expf(mrun - mnew);
        mrun = mnew;
        float psum = 0.f;
#pragma unroll
        for (int kt2 = 0; kt2 < 8; ++kt2) {
            float e0 = __expf(st[kt2][0] - mrun);
            float e1 = __expf(st[kt2][1] - mrun);
            float e2 = __expf(st[kt2][2] - mrun);
            float e3 = __expf(st[kt2][3] - mrun);
            psum += (e0 + e1) + (e2 + e3);
            ushort4 o; o.x = f2bf(e0); o.y = f2bf(e1); o.z = f2bf(e2); o.w = f2bf(e3);
            *(ushort4*)(PsW + la * 136 + kt2 * 16 + quad * 4) = o;   // P[q=la][k]
        }
        psum += __shfl_xor(psum, 16, 64);
        psum += __shfl_xor(psum, 32, 64);
        lrun = lrun * f + psum;
        // rescale O accumulator: f is per q-row; oacc rows are q = quad*4+r
        float fr[4];
#pragma unroll
        for (int r = 0; r < 4; ++r) fr[r] = __shfl(f, quad * 4 + r, 64);
#pragma unroll
        for (int dt2 = 0; dt2 < 4; ++dt2)
#pragma unroll
            for (int r = 0; r < 4; ++r) oacc[dt2][r] *= fr[r];
        // full barrier: all P writes visible before PV fragment reads
        __syncthreads();
        // PV: A = P rows (la), B = Vt rows (d = dt2*16+la)
#pragma unroll
        for (int ks = 0; ks < 4; ++ks) {
            short8 pa = *(const short8*)(PsW + la * 136 + ks * 32 + quad * 8);
#pragma unroll
            for (int dt2 = 0; dt2 < 4; ++dt2) {
                short8 bv = *(const short8*)(Vt + (dt2 * 16 + la) * 136 + ks * 32 + quad * 8);
                oacc[dt2] = __builtin_amdgcn_mfma_f32_16x16x32_bf16(pa, bv, oacc[dt2], 0, 0, 0);
            }
        }
    }

    // epilogue: divide by softmax sum, write out
    float linv = 1.0f / lrun;
    float lr[4];
#pragma unroll
    for (int r = 0; r < 4; ++r) lr[r] = __shfl(linv, quad * 4 + r, 64);
#pragma unroll
    for (int dt2 = 0; dt2 < 4; ++dt2) {
        int d = h * 64 + dt2 * 16 + la;
#pragma unroll
        for (int r = 0; r < 4; ++r) {
            int q = q0 + w * 16 + quad * 4 + r;
            attn_out[(rowbase + q) * 1024 + d] = f2bf(oacc[dt2][r] * lr[r]);
        }
    }
}

// ---------------------------------------------------------------------------
// residual + LayerNorm, bf16 in/out (in-place on z), fp32 internals
// ---------------------------------------------------------------------------
__global__ __launch_bounds__(256) void resid_ln(
    const unsigned short* __restrict__ z_in, const unsigned short* __restrict__ br,
    const unsigned short* __restrict__ g, const unsigned short* __restrict__ bb,
    unsigned short* __restrict__ z_out)
{
    __shared__ float red[4];
    const int m = blockIdx.x, t = threadIdx.x;
    float v[4];
#pragma unroll
    for (int u = 0; u < 4; ++u) {
        int e = t + u * 256;
        v[u] = bf2f(z_in[(size_t)m * 1024 + e]) + bf2f(br[(size_t)m * 1024 + e]);
    }
    float s = v[0] + v[1] + v[2] + v[3];
#pragma unroll
    for (int off = 32; off >= 1; off >>= 1) s += __shfl_xor(s, off, 64);
    if ((t & 63) == 0) red[t >> 6] = s;
    __syncthreads();
    float mean = (red[0] + red[1] + red[2] + red[3]) * (1.0f / 1024.0f);
    __syncthreads();
    float q = 0.f;
#pragma unroll
    for (int u = 0; u < 4; ++u) { float d = v[u] - mean; q += d * d; }
#pragma unroll
    for (int off = 32; off >= 1; off >>= 1) q += __shfl_xor(q, off, 64);
    if ((t & 63) == 0) red[t >> 6] = q;
    __syncthreads();
    float var = (red[0] + red[1] + red[2] + red[3]) * (1.0f / 1024.0f);
    float inv = rsqrtf(var + 1e-5f);
#pragma unroll
    for (int u = 0; u < 4; ++u) {
        int e = t + u * 256;
        float o = (v[u] - mean) * inv * bf2f(g[e]) + bf2f(bb[e]);
        z_out[(size_t)m * 1024 + e] = f2bf(o);
    }
}

// ---------------------------------------------------------------------------
// pinv pieces (inputs already converted to bf16)
// ---------------------------------------------------------------------------
__global__ void transpose_wobs(const unsigned short* __restrict__ W, unsigned short* __restrict__ WT)
{
    int idx = blockIdx.x * 256 + threadIdx.x;     // 131072 total
    int o = idx >> 10, e = idx & 1023;
    WT[e * 128 + o] = W[idx];
}

__global__ void compute_G(const unsigned short* __restrict__ WT, float* __restrict__ G)
{
    int i = blockIdx.x, j = threadIdx.x;          // 128 x 128
    float s = 0.f;
    for (int e = 0; e < 1024; ++e)
        s += bf2f(WT[e * 128 + i]) * bf2f(WT[e * 128 + j]);
    G[i * 128 + j] = s;
}

// sweep operator: sweeping all pivots of SPD A in place yields -A^{-1}.
// Register-resident: thread owns column j = t&127, rows i = (t>>7) + 8u
// (16 f32 in VGPRs, statically indexed: ku-unrolled outer loop, k = 8*ku+kib).
// Per pivot only row-k / col-k go through 512B LDS buffers; update is 16
// register FMAs. Same op order as the LDS version -> identical numerics.
__global__ __launch_bounds__(1024) void sweep_inv(const float* __restrict__ G, float* __restrict__ Gi)
{
    __shared__ float rowbuf[128];
    __shared__ float colbuf[128];
    const int t = threadIdx.x;
    const int j = t & 127;                        // column (consecutive within wave)
    const int ib = t >> 7;                        // row base 0..7 (wave-uniform)
    float vals[16];
#pragma unroll
    for (int u = 0; u < 16; ++u)
        vals[u] = G[(ib + u * 8) * 128 + j];      // coalesced

#pragma unroll
    for (int ku = 0; ku < 16; ++ku) {
        for (int kib = 0; kib < 8; ++kib) {       // pivot k = 8*ku + kib (sequential)
            const int k = ku * 8 + kib;
            if (ib == kib) rowbuf[j] = vals[ku];  // row-k snapshot (stride-1, 2/bank)
            if (j == k) {
#pragma unroll
                for (int u = 0; u < 16; ++u) colbuf[ib + u * 8] = vals[u];  // col-k
            }
            __syncthreads();                      // snapshots visible
            float d = rowbuf[k];                  // M[k][k], broadcast
            float p = 1.0f / d;
            float rj = rowbuf[j];                 // M[k][j], conflict-free
#pragma unroll
            for (int u = 0; u < 16; ++u) {
                int i = ib + u * 8;
                float cv = colbuf[i];             // M[i][k], broadcast
                float nv;
                if (i == k && j == k)      nv = -p;
                else if (i == k)           nv = rj * p;
                else if (j == k)           nv = cv * p;
                else                       nv = vals[u] - cv * rj * p;
                vals[u] = nv;
            }
            __syncthreads();                      // reads done before next writes
        }
    }
#pragma unroll
    for (int u = 0; u < 16; ++u)
        Gi[(ib + u * 8) * 128 + j] = -vals[u];
}

__global__ void embed_y(const unsigned short* __restrict__ x, const float* __restrict__ Gi,
                        float* __restrict__ y)
{
    int m = blockIdx.x, t = threadIdx.x;  // 128 threads
    float s = 0.f;
    for (int o = 0; o < 128; ++o)
        s += bf2f(x[(size_t)m * 128 + o]) * Gi[o * 128 + t];
    y[(size_t)m * 128 + t] = s;
}

__global__ __launch_bounds__(256) void embed_z(const float* __restrict__ y,
                                               const unsigned short* __restrict__ Wobs,
                                               unsigned short* __restrict__ zb)
{
    int m = blockIdx.x, t = threadIdx.x;
    int s = m & 511;
    float accv[4] = {0.f, 0.f, 0.f, 0.f};
    for (int o = 0; o < 128; ++o) {
        float yv = y[(size_t)m * 128 + o];
#pragma unroll
        for (int u = 0; u < 4; ++u) {
            int e = t + u * 256;
            accv[u] += yv * bf2f(Wobs[o * 1024 + e]);
        }
    }
#pragma unroll
    for (int u = 0; u < 4; ++u) {
        int e = t + u * 256;
        float freq = __expf(-0.008994473019508f * (float)(e & ~1));
        float ang = (float)s * freq;
        float pe = (e & 1) ? cosf(ang) : sinf(ang);
        float v = accv[u] + pe;
        zb[(size_t)m * 1024 + e] = f2bf(v);
    }
}

// ---------------------------------------------------------------------------
extern "C" void kernel_launch(void* const* d_in, const int* in_sizes, int n_in,
                              void* d_out, int out_size, void* d_ws, size_t ws_size,
                              hipStream_t stream)
{
    const void* x_raw     = d_in[0];
    const void* Wobs_raw  = d_in[1];
    const void* Wqkv_raw  = d_in[2];
    const void* Wo_raw    = d_in[3];
    const void* bo_raw    = d_in[4];
    const void* ln1g_raw  = d_in[5];
    const void* ln1b_raw  = d_in[6];
    const void* W1_raw    = d_in[7];
    const void* b1_raw    = d_in[8];
    const void* W2_raw    = d_in[9];
    const void* b2_raw    = d_in[10];
    const void* ln2g_raw  = d_in[11];
    const void* ln2b_raw  = d_in[12];

    char* ws = (char*)d_ws;
    constexpr size_t OFF_G    = 0;                                  // 64 KB
    constexpr size_t OFF_GI   = OFF_G    + 65536;                   // 64 KB
    constexpr size_t OFF_Y    = OFF_GI   + 65536;                   // 2 MB fp32
    constexpr size_t OFF_WT   = OFF_Y    + (size_t)4096 * 128 * 4;  // 256 KB
    constexpr size_t OFF_ZB   = OFF_WT   + (size_t)1024 * 128 * 2;  // 8 MB
    constexpr size_t OFF_QKV  = OFF_ZB   + (size_t)4096 * 1024 * 2; // 24 MB
    constexpr size_t OFF_ATT  = OFF_QKV  + (size_t)4096 * 3072 * 2; // 8 MB
    constexpr size_t OFF_FFN1 = OFF_QKV;                            // 32 MB alias (qkv+att dead)
    constexpr size_t OFF_SCR  = OFF_ATT  + (size_t)4096 * 1024 * 2; // 8 MB
    constexpr size_t OFF_XBF  = OFF_SCR  + (size_t)4096 * 1024 * 2; // 1 MB
    constexpr size_t OFF_WOBS = OFF_XBF  + (size_t)524288 * 2;      // 256 KB
    constexpr size_t OFF_CVT  = OFF_WOBS + (size_t)131072 * 2;      // 8 MB (max weight slice)
    constexpr size_t OFF_BO   = OFF_CVT  + (size_t)4096 * 1024 * 2;
    constexpr size_t OFF_B1   = OFF_BO   + 8192 * 2;
    constexpr size_t OFF_B2   = OFF_B1   + 32768 * 2;
    constexpr size_t OFF_L1G  = OFF_B2   + 8192 * 2;
    constexpr size_t OFF_L1B  = OFF_L1G  + 8192 * 2;
    constexpr size_t OFF_L2G  = OFF_L1B  + 8192 * 2;
    constexpr size_t OFF_L2B  = OFF_L2G  + 8192 * 2;
    constexpr size_t OFF_FLAG = OFF_L2B  + 8192 * 2;                // 4 B

    float* G             = (float*)(ws + OFF_G);
    float* Gi            = (float*)(ws + OFF_GI);
    float* y             = (float*)(ws + OFF_Y);
    unsigned short* WT   = (unsigned short*)(ws + OFF_WT);
    unsigned short* zb   = (unsigned short*)(ws + OFF_ZB);
    unsigned short* qkvb = (unsigned short*)(ws + OFF_QKV);
    unsigned short* attnb= (unsigned short*)(ws + OFF_ATT);
    unsigned short* ffn1 = (unsigned short*)(ws + OFF_FFN1);
    unsigned short* scr  = (unsigned short*)(ws + OFF_SCR);
    unsigned short* xbf  = (unsigned short*)(ws + OFF_XBF);
    unsigned short* wobs = (unsigned short*)(ws + OFF_WOBS);
    unsigned short* cvtb = (unsigned short*)(ws + OFF_CVT);
    unsigned short* boB  = (unsigned short*)(ws + OFF_BO);
    unsigned short* b1B  = (unsigned short*)(ws + OFF_B1);
    unsigned short* b2B  = (unsigned short*)(ws + OFF_B2);
    unsigned short* l1g  = (unsigned short*)(ws + OFF_L1G);
    unsigned short* l1b  = (unsigned short*)(ws + OFF_L1B);
    unsigned short* l2g  = (unsigned short*)(ws + OFF_L2G);
    unsigned short* l2b  = (unsigned short*)(ws + OFF_L2B);
    int* flag            = (int*)(ws + OFF_FLAG);

    sniff_dtype<<<1, 256, 0, stream>>>((const unsigned int*)Wobs_raw, flag);

    auto cvt = [&](const void* src, size_t off, unsigned short* dst, int n) {
        cvt_in<<<(n + 1023) / 1024, 256, 0, stream>>>(src, off, dst, n, flag);
    };

    // small persistent conversions
    cvt(x_raw, 0, xbf, 524288);
    cvt(Wobs_raw, 0, wobs, 131072);
    cvt(bo_raw, 0, boB, 8192);
    cvt(b1_raw, 0, b1B, 32768);
    cvt(b2_raw, 0, b2B, 8192);
    cvt(ln1g_raw, 0, l1g, 8192);
    cvt(ln1b_raw, 0, l1b, 8192);
    cvt(ln2g_raw, 0, l2g, 8192);
    cvt(ln2b_raw, 0, l2b, 8192);

    transpose_wobs<<<512, 256, 0, stream>>>(wobs, WT);
    compute_G<<<128, 128, 0, stream>>>(WT, G);
    sweep_inv<<<1, 1024, 0, stream>>>(G, Gi);
    embed_y<<<4096, 128, 0, stream>>>(xbf, Gi, y);
    embed_z<<<4096, 256, 0, stream>>>(y, wobs, zb);

    for (int l = 0; l < 8; ++l) {
        // QKV
        cvt(Wqkv_raw, (size_t)l * 3072 * 1024, cvtb, 3072 * 1024);
        gemm_bt<<<dim3(24, 32), 256, 0, stream>>>(zb, cvtb, nullptr, qkvb, 4096, 3072, 1024, 0);
        attn_kernel<<<dim3(8, 128), 256, 0, stream>>>(qkvb, attnb);
        // Wo
        cvt(Wo_raw, (size_t)l * 1024 * 1024, cvtb, 1024 * 1024);
        gemm_bt<<<dim3(8, 32), 256, 0, stream>>>(attnb, cvtb, boB + (size_t)l * 1024, scr, 4096, 1024, 1024, 0);
        resid_ln<<<4096, 256, 0, stream>>>(zb, scr, l1g + (size_t)l * 1024, l1b + (size_t)l * 1024, zb);
        // FFN
        cvt(W1_raw, (size_t)l * 4096 * 1024, cvtb, 4096 * 1024);
        gemm_bt<<<dim3(32, 32), 256, 0, stream>>>(zb, cvtb, b1B + (size_t)l * 4096, ffn1, 4096, 4096, 1024, 1);
        cvt(W2_raw, (size_t)l * 1024 * 4096, cvtb, 1024 * 4096);
        gemm_bt<<<dim3(8, 32), 256, 0, stream>>>(ffn1, cvtb, b2B + (size_t)l * 1024, scr, 4096, 1024, 4096, 0);
        resid_ln<<<4096, 256, 0, stream>>>(zb, scr, l2g + (size_t)l * 1024, l2b + (size_t)l * 1024, zb);
    }

    // final projection into scr (bf16), then dtype-correct output write
    gemm_bt<<<dim3(1, 32), 256, 0, stream>>>(zb, wobs, nullptr, scr, 4096, 128, 1024, 0);
    write_out<<<(out_size + 255) / 256, 256, 0, stream>>>(scr, d_out, out_size, flag);
}